// Round 1
// baseline (237.083 us; speedup 1.0000x reference)
//
#include <hip/hip_runtime.h>
#include <hip/hip_bf16.h>

#define MUL_Sc 256
#define MUL_Vc 128
#define DIM_Hc 640
#define IN_COLS 644
#define KFEAT 1024
#define NT 32

#define C0F 0.05103103630798287f
#define INV_SQRT3F 0.57735026918962576f

typedef __attribute__((ext_vector_type(8))) short short8;
typedef __attribute__((ext_vector_type(4))) float f32x4;

#define MFMA(a, b, c) __builtin_amdgcn_mfma_f32_16x16x32_bf16((a), (b), (c), 0, 0, 0)

__device__ __forceinline__ unsigned short f2bf(float x) {
    union { float f; unsigned u; } v; v.f = x;
    unsigned r = v.u + 0x7fffu + ((v.u >> 16) & 1u);   // RNE
    return (unsigned short)(r >> 16);
}
__device__ __forceinline__ float bf2f(unsigned short h) {
    union { unsigned u; float f; } v; v.u = ((unsigned)h) << 16;
    return v.f;
}

// ---- weight prep: fp32 [k][col] -> bf16 transposed [col][k] in d_ws ----
// layout: WT_sg 384x384 (cols 0..255 = scal via W_ss/W_vv, 256..383 = gate via W_ss_g/W_vv_g)
//         WT_sv 128x256, WT_vs 128x128
__global__ void prep_weights(const float* __restrict__ Wss, const float* __restrict__ Wvv,
                             const float* __restrict__ Wssg, const float* __restrict__ Wvvg,
                             const float* __restrict__ Wsv, const float* __restrict__ Wvs,
                             unsigned short* __restrict__ wt) {
    int i = blockIdx.x * 256 + threadIdx.x;
    const int N_SG = 384 * 384;
    const int N_SV = 128 * 256;
    const int N_VS = 128 * 128;
    if (i < N_SG) {
        int col = i / 384, k = i % 384;
        float v;
        if (col < 256) v = (k < 256) ? Wss[k * 256 + col] : Wvv[(k - 256) * 256 + col];
        else { int c = col - 256; v = (k < 256) ? Wssg[k * 128 + c] : Wvvg[(k - 256) * 128 + c]; }
        wt[i] = f2bf(v);
    } else if (i < N_SG + N_SV) {
        int j = i - N_SG; int col = j >> 8, k = j & 255;
        wt[i] = f2bf(Wsv[k * 128 + col]);
    } else if (i < N_SG + N_SV + N_VS) {
        int j = i - N_SG - N_SV; int col = j >> 7, k = j & 127;
        wt[i] = f2bf(Wvs[k * 128 + col]);
    }
}

// ---- fused main kernel ----
// feature row per node (bf16, 1024): [ s0(0:256) | dot(256:384) | xs(384:640) | xv_k0(640:768) | xv_k1(768:896) | xv_k2(896:1024) ]
__global__ __launch_bounds__(512, 4)
void fused_main(const float* __restrict__ din, const unsigned short* __restrict__ wt,
                const float* __restrict__ bias, float* __restrict__ out, int N) {
    __shared__ unsigned short feat[NT * KFEAT];    // 64 KB, XOR-swizzled by (node&7)<<4
    __shared__ unsigned short sgate[NT * MUL_Vc];  // 8 KB: sigmoid(gate) as bf16
    __shared__ float psv[NT * 4];                  // ps, pv0, pv1, pv2 per node

    const int tid = threadIdx.x;
    const int n0 = blockIdx.x * NT;

    // ---------------- staging: 16 threads per node ----------------
    {
        const int g = tid >> 4;       // local node 0..31
        const int j = tid & 15;
        int n = n0 + g; if (n >= N) n = N - 1;
        const float* row = din + (size_t)n * IN_COLS;
        float ps  = row[DIM_Hc];
        float pv0 = row[DIM_Hc + 1], pv1 = row[DIM_Hc + 2], pv2 = row[DIM_Hc + 3];
        if (j == 0) { psv[g*4+0] = ps; psv[g*4+1] = pv0; psv[g*4+2] = pv1; psv[g*4+3] = pv2; }
        char* fb = (char*)feat;
        const int swz  = (g & 7) << 4;
        const int rowb = g * (KFEAT * 2);
        #pragma unroll
        for (int it = 0; it < 8; ++it) {           // xs -> s0 + xs planes
            int c = 2 * j + 32 * it;
            float2 x = *(const float2*)(row + c);
            unsigned xsp = (unsigned)f2bf(x.x)      | ((unsigned)f2bf(x.y)      << 16);
            unsigned s0p = (unsigned)f2bf(x.x * ps) | ((unsigned)f2bf(x.y * ps) << 16);
            *(unsigned*)(fb + ((rowb + c * 2) ^ swz))         = s0p;
            *(unsigned*)(fb + ((rowb + (384 + c) * 2) ^ swz)) = xsp;
        }
        #pragma unroll
        for (int it = 0; it < 4; ++it) {           // xv -> dot + 3 k-planes
            int u = 2 * j + 32 * it;
            const float* p = row + MUL_Sc + 3 * u;
            float a0 = p[0], a1 = p[1], a2 = p[2], b0 = p[3], b1 = p[4], b2 = p[5];
            float d0 = (a0 * pv0 + a1 * pv1 + a2 * pv2) * INV_SQRT3F;
            float d1 = (b0 * pv0 + b1 * pv1 + b2 * pv2) * INV_SQRT3F;
            *(unsigned*)(fb + ((rowb + (256 + u) * 2) ^ swz)) = (unsigned)f2bf(d0) | ((unsigned)f2bf(d1) << 16);
            *(unsigned*)(fb + ((rowb + (640 + u) * 2) ^ swz)) = (unsigned)f2bf(a0) | ((unsigned)f2bf(b0) << 16);
            *(unsigned*)(fb + ((rowb + (768 + u) * 2) ^ swz)) = (unsigned)f2bf(a1) | ((unsigned)f2bf(b1) << 16);
            *(unsigned*)(fb + ((rowb + (896 + u) * 2) ^ swz)) = (unsigned)f2bf(a2) | ((unsigned)f2bf(b2) << 16);
        }
    }
    __syncthreads();

    const int wave = tid >> 6;            // 0..7
    const int lane = tid & 63;
    const int l15  = lane & 15;
    const int lkb  = (lane >> 4) << 3;    // k sub-offset: 0,8,16,24
    const char* fbr = (const char*)feat;
    const int swzr = (l15 & 7) << 4;

    const unsigned short* WTsg = wt;
    const unsigned short* WTsv = wt + 384 * 384;
    const unsigned short* WTvs = wt + 384 * 384 + 128 * 256;

    // ---------------- scal+gate GEMM: K=384, 24 col-tiles, wave does {w, w+8, w+16} ----------------
    f32x4 accS[3][2];
    #pragma unroll
    for (int t = 0; t < 3; ++t) { accS[t][0] = (f32x4){0,0,0,0}; accS[t][1] = (f32x4){0,0,0,0}; }

    #pragma unroll
    for (int ks = 0; ks < 12; ++ks) {
        int kf = ks * 32 + lkb;
        short8 a0 = *(const short8*)(fbr + (((0  + l15) * 2048 + kf * 2) ^ swzr));
        short8 a1 = *(const short8*)(fbr + (((16 + l15) * 2048 + kf * 2) ^ swzr));
        #pragma unroll
        for (int t = 0; t < 3; ++t) {
            int ct = wave + t * 8;
            short8 b = *(const short8*)(WTsg + (ct * 16 + l15) * 384 + ks * 32 + lkb);
            accS[t][0] = MFMA(a0, b, accS[t][0]);
            accS[t][1] = MFMA(a1, b, accS[t][1]);
        }
    }
    {   // epilogue: scal -> silu -> global ; gate -> sigmoid -> LDS
        const int rbase = (lane >> 4) << 2;
        #pragma unroll
        for (int t = 0; t < 3; ++t) {
            int ct = wave + t * 8;
            int col = ct * 16 + l15;
            if (ct < 16) {
                float bc = bias[col];
                #pragma unroll
                for (int s = 0; s < 2; ++s)
                #pragma unroll
                for (int i = 0; i < 4; ++i) {
                    int nl = s * 16 + rbase + i;
                    int n = n0 + nl;
                    if (n < N) {
                        float sc = C0F * accS[t][s][i] + bc;
                        out[(size_t)n * DIM_Hc + col] = sc / (1.f + __expf(-sc));
                    }
                }
            } else {
                int gc = col - 256;
                #pragma unroll
                for (int s = 0; s < 2; ++s)
                #pragma unroll
                for (int i = 0; i < 4; ++i) {
                    int nl = s * 16 + rbase + i;
                    float gt = C0F * accS[t][s][i];
                    sgate[nl * MUL_Vc + gc] = f2bf(1.f / (1.f + __expf(-gt)));
                }
            }
        }
    }

    // ---------------- vec GEMMs: a1 (K=256) + v2_k (K=128 x3), wave owns u-tile = wave ----------------
    f32x4 accA[2], accV[3][2];
    accA[0] = (f32x4){0,0,0,0}; accA[1] = (f32x4){0,0,0,0};
    #pragma unroll
    for (int k = 0; k < 3; ++k) { accV[k][0] = (f32x4){0,0,0,0}; accV[k][1] = (f32x4){0,0,0,0}; }
    const int ut = wave;

    #pragma unroll
    for (int ks = 0; ks < 8; ++ks) {
        short8 b = *(const short8*)(WTsv + (ut * 16 + l15) * 256 + ks * 32 + lkb);
        int kf = 384 + ks * 32 + lkb;
        short8 a0 = *(const short8*)(fbr + (((0  + l15) * 2048 + kf * 2) ^ swzr));
        short8 a1 = *(const short8*)(fbr + (((16 + l15) * 2048 + kf * 2) ^ swzr));
        accA[0] = MFMA(a0, b, accA[0]);
        accA[1] = MFMA(a1, b, accA[1]);
    }
    #pragma unroll
    for (int ks = 0; ks < 4; ++ks) {
        short8 b = *(const short8*)(WTvs + (ut * 16 + l15) * 128 + ks * 32 + lkb);
        #pragma unroll
        for (int k = 0; k < 3; ++k) {
            int kf = 640 + 128 * k + ks * 32 + lkb;
            short8 a0 = *(const short8*)(fbr + (((0  + l15) * 2048 + kf * 2) ^ swzr));
            short8 a1 = *(const short8*)(fbr + (((16 + l15) * 2048 + kf * 2) ^ swzr));
            accV[k][0] = MFMA(a0, b, accV[k][0]);
            accV[k][1] = MFMA(a1, b, accV[k][1]);
        }
    }
    __syncthreads();   // sgate complete across all waves

    {   // vec epilogue: vec = C0*(a1*pv + v2*ps) * sigmoid(gate)
        const int rbase = (lane >> 4) << 2;
        int u = ut * 16 + l15;
        #pragma unroll
        for (int s = 0; s < 2; ++s)
        #pragma unroll
        for (int i = 0; i < 4; ++i) {
            int nl = s * 16 + rbase + i;
            int n = n0 + nl;
            if (n >= N) continue;
            float sg  = bf2f(sgate[nl * MUL_Vc + u]);
            float ps  = psv[nl * 4 + 0];
            float pv0 = psv[nl * 4 + 1], pv1 = psv[nl * 4 + 2], pv2 = psv[nl * 4 + 3];
            float av = accA[s][i];
            size_t ob = (size_t)n * DIM_Hc + MUL_Sc + 3 * u;
            out[ob + 0] = C0F * (av * pv0 + accV[0][s][i] * ps) * sg;
            out[ob + 1] = C0F * (av * pv1 + accV[1][s][i] * ps) * sg;
            out[ob + 2] = C0F * (av * pv2 + accV[2][s][i] * ps) * sg;
        }
    }
}

extern "C" void kernel_launch(void* const* d_in, const int* in_sizes, int n_in,
                              void* d_out, int out_size, void* d_ws, size_t ws_size,
                              hipStream_t stream) {
    const float* din  = (const float*)d_in[0];
    const float* Wss  = (const float*)d_in[1];
    const float* Wvv  = (const float*)d_in[2];
    const float* Wssg = (const float*)d_in[3];
    const float* Wvvg = (const float*)d_in[4];
    const float* Wsv  = (const float*)d_in[5];
    const float* Wvs  = (const float*)d_in[6];
    const float* bias = (const float*)d_in[7];
    float* out = (float*)d_out;
    unsigned short* wt = (unsigned short*)d_ws;

    const size_t WT_BYTES = (size_t)(384 * 384 + 128 * 256 + 128 * 128) * 2;
    if (ws_size < WT_BYTES) return;  // workspace too small (not expected)

    int N = in_sizes[0] / IN_COLS;

    int prep_total = 384 * 384 + 128 * 256 + 128 * 128;
    prep_weights<<<(prep_total + 255) / 256, 256, 0, stream>>>(Wss, Wvv, Wssg, Wvvg, Wsv, Wvs, wt);

    int nblocks = (N + NT - 1) / NT;
    fused_main<<<nblocks, 512, 0, stream>>>(din, wt, bias, out, N);
}